// Round 13
// baseline (98.767 us; speedup 1.0000x reference)
//
#include <hip/hip_runtime.h>
#include <hip/hip_bf16.h>

#define IN_FEAT 4096
#define OUT_FEAT 4096
#define FP_FEAT 256
#define INT_FEAT 3840
#define TOKENS 4096
#define PACKED_W (INT_FEAT / 2)  // 1920

#define NT_I8 60          // int K-tiles (K=64 i8 each)
#define NT_ALL 68         // + 8 fp sub-tiles (K=32 bf16 each)

typedef __attribute__((ext_vector_type(8))) short short8;
typedef __attribute__((ext_vector_type(4))) float f32x4;
typedef __attribute__((ext_vector_type(4))) int   int32x4;

// workspace layout (bytes)
#define AQ8_OFF   0u
#define WB8_OFF   16777216u
#define AFP_OFF   33554432u
#define WFP_OFF   35651584u
#define SCALE_OFF 37748736u
#define ZERO_OFF  37765120u
#define WS_NEED   37781504u

// ------------------------------------------------- fused quantize + unpack ---
__global__ __launch_bounds__(256) void prep_kernel(
    const float* __restrict__ x,
    const int* __restrict__ int_idx_raw,
    const int* __restrict__ fp_idx_raw,
    const int* __restrict__ wpacked_raw,
    const float* __restrict__ fpw,
    const float* __restrict__ wscale,
    signed char* __restrict__ Aq8,
    __hip_bfloat16* __restrict__ Afp,
    signed char* __restrict__ Wb8,
    __hip_bfloat16* __restrict__ Wfp,
    float* __restrict__ scale_ws,
    float* __restrict__ zero_ws)
{
    const int t = threadIdx.x;
    if (blockIdx.x < TOKENS) {
        const int m = blockIdx.x;
        const float* xr = x + (size_t)m * IN_FEAT;
        const bool is64 = (int_idx_raw[1] == 0) && (int_idx_raw[3] == 0);

        float v[15];
        float mn = 1e30f, mx = -1e30f;
#pragma unroll
        for (int j = 0; j < 15; ++j) {
            int k = t + j * 256;
            int idx = is64 ? int_idx_raw[2 * k] : int_idx_raw[k];
            float f = xr[idx];
            v[j] = f;
            mn = fminf(mn, f);
            mx = fmaxf(mx, f);
        }
#pragma unroll
        for (int off = 1; off < 64; off <<= 1) {
            mn = fminf(mn, __shfl_xor(mn, off));
            mx = fmaxf(mx, __shfl_xor(mx, off));
        }
        __shared__ float smn[4], smx[4];
        int wid = t >> 6, lane = t & 63;
        if (lane == 0) { smn[wid] = mn; smx[wid] = mx; }
        __syncthreads();
        if (t == 0) {
            float rmn = fminf(fminf(smn[0], smn[1]), fminf(smn[2], smn[3]));
            float rmx = fmaxf(fmaxf(smx[0], smx[1]), fmaxf(smx[2], smx[3]));
            float sc = fmaxf((rmx - rmn) / 15.0f, 1e-8f);
            smn[0] = rmn;
            smx[0] = sc;
            scale_ws[m] = sc;
            zero_ws[m] = rmn;
        }
        __syncthreads();
        const float zero = smn[0];
        const float sc = smx[0];

        signed char* ar = Aq8 + (size_t)m * INT_FEAT;
#pragma unroll
        for (int j = 0; j < 15; ++j) {
            int k = t + j * 256;
            float q = rintf((v[j] - zero) / sc) - 8.0f;  // IEEE div+rndne == np
            q = fminf(fmaxf(q, -8.0f), 7.0f);
            ar[k] = (signed char)(int)q;                 // exact small int
        }
        int fpi = is64 ? fp_idx_raw[2 * t] : fp_idx_raw[t];
        Afp[(size_t)m * FP_FEAT + t] = __float2bfloat16(xr[fpi] / sc);
    } else {
        const int n = blockIdx.x - TOKENS;
        bool is_i32 = true;
#pragma unroll
        for (int j = 0; j < 8; ++j) {
            unsigned w = (unsigned)wpacked_raw[j];
            if (w > 0xFFu) is_i32 = false;
        }
        short* wo = (short*)(Wb8 + (size_t)n * INT_FEAT);
#pragma unroll
        for (int j = 0; j < 8; ++j) {
            int k = t + j * 256;
            if (k < PACKED_W) {
                int p = is_i32 ? wpacked_raw[(size_t)n * PACKED_W + k]
                               : ((const unsigned char*)wpacked_raw)[(size_t)n * PACKED_W + k];
                int lo = p & 15; if (lo >= 8) lo -= 16;
                int hi = (p >> 4) & 15; if (hi >= 8) hi -= 16;
                wo[k] = (short)(((unsigned char)lo) | ((unsigned short)(unsigned char)hi << 8));
            }
        }
        float wsn = wscale[n];
        Wfp[(size_t)n * FP_FEAT + t] = __float2bfloat16(fpw[(size_t)n * FP_FEAT + t] / wsn);
    }
}

// --------------------------------------- GEMM 256x256 i8 8-phase + bf16 tail
// m201-faithful phase discipline on the i8 loop: 4 phases per K-tile, each
// {ds_read subtile; 1 gload stage; [vmcnt(8) at P3]; s_barrier;
//  asm lgkmcnt(0); sched_barrier(0); setprio(1); 8 MFMA; setprio(0);
//  s_barrier}.  b-frags read once (P0), a-pair per phase.  vmcnt counted
// (8 = stages of vt+2,vt+3 in flight), never 0 in steady state.
// Hazards: stage target buf[(vt+3)&3] == buf[(vt-1)&3] -- its last reads
// completed at vt-1/P3's lgkmcnt(0) before that phase's mid-barrier; the
// stage is issued after vt-1/P3's end-barrier.  Reads of buf[vt+1] at
// vt+1/P0 are safe: every wave passed its vmcnt(8) (drains vt+1's 4
// stages) before vt/P3's mid-barrier.
// Numerics: one MFMA per acc element per tile in identical order to r12
// -> absmax must stay bit-exact 0.1992188.

__global__ __launch_bounds__(512, 2) void gemm256_i8(
    const signed char* __restrict__ Aq8,
    const __hip_bfloat16* __restrict__ Afp,
    const signed char* __restrict__ Wb8,
    const __hip_bfloat16* __restrict__ Wfp,
    const float* __restrict__ scale_ws,
    const float* __restrict__ zero_ws,
    const float* __restrict__ wscale,
    const float* __restrict__ reduced,
    const float* __restrict__ bias,
    float* __restrict__ out)
{
    __shared__ __align__(16) char lds[131072];  // 4 x (16K A + 16K B)

    const int t = threadIdx.x;
    const int lane = t & 63, wid = t >> 6;
    const int wr = wid >> 2;                   // 0..1
    const int wc = wid & 3;                    // 0..3
    const int r16 = lane & 15;
    const int kg = lane >> 4;                  // 0..3

    // XCD-aware block swizzle (256 blocks, 8 XCDs)
    const int bid = blockIdx.x;
    const int sb = (bid & 7) * 32 + (bid >> 3);
    const int tileM = (sb >> 4) * 256;
    const int tileN = (sb & 15) * 256;

    // staging geometry: 1024 16B-chunks per operand tile, 2 per thread
    const int id0 = t, id1 = 512 + t;
    const int r0 = id0 >> 2, c0 = id0 & 3;
    const int r1 = id1 >> 2, c1 = id1 & 3;
    const int sw0 = ((c0 ^ ((r0 >> 1) & 3)) << 4);
    const int sw1 = ((c1 ^ ((r1 >> 1) & 3)) << 4);
    const char* a8_0 = (const char*)Aq8 + (size_t)(tileM + r0) * INT_FEAT + sw0;
    const char* a8_1 = (const char*)Aq8 + (size_t)(tileM + r1) * INT_FEAT + sw1;
    const char* b8_0 = (const char*)Wb8 + (size_t)(tileN + r0) * INT_FEAT + sw0;
    const char* b8_1 = (const char*)Wb8 + (size_t)(tileN + r1) * INT_FEAT + sw1;
    const char* af_0 = (const char*)Afp + (size_t)(tileM + r0) * 512 + sw0;
    const char* af_1 = (const char*)Afp + (size_t)(tileM + r1) * 512 + sw1;
    const char* bf_0 = (const char*)Wfp + (size_t)(tileN + r0) * 512 + sw0;
    const char* bf_1 = (const char*)Wfp + (size_t)(tileN + r1) * 512 + sw1;
    const int dst0 = id0 << 4, dst1 = id1 << 4;

    // one 16B gload_lds for chunk j of virtual tile vt into buffer bufB
    auto stage_one = [&](int vt, int bufB, int j) {
        const bool i8p = vt < NT_I8;
        const int ko = i8p ? vt * 64 : (vt - NT_I8) * 64;
        const char* p; int d;
        switch (j) {
            case 0:  p = (i8p ? a8_0 : af_0) + ko; d = dst0;         break;
            case 1:  p = (i8p ? a8_1 : af_1) + ko; d = dst1;         break;
            case 2:  p = (i8p ? b8_0 : bf_0) + ko; d = 16384 + dst0; break;
            default: p = (i8p ? b8_1 : bf_1) + ko; d = 16384 + dst1; break;
        }
        __builtin_amdgcn_global_load_lds(
            (const __attribute__((address_space(1))) void*)p,
            (__attribute__((address_space(3))) void*)(lds + bufB + d), 16, 0, 0);
    };

    // fragment read byte-offsets (dtype-independent: 64B rows, 16B frags)
    int aOff[8], bOff[4];
#pragma unroll
    for (int mf = 0; mf < 8; ++mf) {
        int ra = wr * 128 + mf * 16 + r16;
        aOff[mf] = ra * 64 + ((((ra >> 1) & 3) ^ kg) << 4);
    }
#pragma unroll
    for (int nf = 0; nf < 4; ++nf) {
        int rb = wc * 64 + nf * 16 + r16;
        bOff[nf] = 16384 + rb * 64 + ((((rb >> 1) & 3) ^ kg) << 4);
    }

    int32x4 acc[8][4];
#pragma unroll
    for (int mf = 0; mf < 8; ++mf)
#pragma unroll
        for (int nf = 0; nf < 4; ++nf)
            acc[mf][nf] = (int32x4){0, 0, 0, 0};

    // prologue: stage tiles 0,1,2; drain tile 0 (vmcnt(8) leaves 1,2 flying)
#pragma unroll
    for (int j = 0; j < 4; ++j) stage_one(0, 0, j);
#pragma unroll
    for (int j = 0; j < 4; ++j) stage_one(1, 32768, j);
#pragma unroll
    for (int j = 0; j < 4; ++j) stage_one(2, 65536, j);
    asm volatile("s_waitcnt vmcnt(8)" ::: "memory");
    __builtin_amdgcn_sched_barrier(0);
    __builtin_amdgcn_s_barrier();
    __builtin_amdgcn_sched_barrier(0);

    // ---- loop 1: 60 i8 K-tiles, 4 phases each (m201 discipline) ----
#define PHASE_I8(P, READS, EXTRA)                                              \
    do {                                                                       \
        READS;                                                                 \
        stage_one(vt + 3, sB, P);                                              \
        EXTRA;                                                                 \
        __builtin_amdgcn_s_barrier();                                          \
        asm volatile("s_waitcnt lgkmcnt(0)" ::: "memory");                     \
        __builtin_amdgcn_sched_barrier(0);                                     \
        __builtin_amdgcn_s_setprio(1);                                         \
        _Pragma("unroll")                                                      \
        for (int nf = 0; nf < 4; ++nf) {                                       \
            acc[2*(P)][nf]   = __builtin_amdgcn_mfma_i32_16x16x64_i8(          \
                aE, bI[nf], acc[2*(P)][nf], 0, 0, 0);                          \
            acc[2*(P)+1][nf] = __builtin_amdgcn_mfma_i32_16x16x64_i8(          \
                aO, bI[nf], acc[2*(P)+1][nf], 0, 0, 0);                        \
        }                                                                      \
        __builtin_amdgcn_s_setprio(0);                                         \
        __builtin_amdgcn_s_barrier();                                          \
    } while (0)

    for (int vt = 0; vt < NT_I8; ++vt) {
        const int bufB = (vt & 3) << 15;
        const int sB = ((vt + 3) & 3) << 15;
        int32x4 bI[4], aE, aO;

        PHASE_I8(0,
            {
                bI[0] = *(const int32x4*)(lds + bufB + bOff[0]);
                bI[1] = *(const int32x4*)(lds + bufB + bOff[1]);
                bI[2] = *(const int32x4*)(lds + bufB + bOff[2]);
                bI[3] = *(const int32x4*)(lds + bufB + bOff[3]);
                aE = *(const int32x4*)(lds + bufB + aOff[0]);
                aO = *(const int32x4*)(lds + bufB + aOff[1]);
            }, {});
        PHASE_I8(1,
            {
                aE = *(const int32x4*)(lds + bufB + aOff[2]);
                aO = *(const int32x4*)(lds + bufB + aOff[3]);
            }, {});
        PHASE_I8(2,
            {
                aE = *(const int32x4*)(lds + bufB + aOff[4]);
                aO = *(const int32x4*)(lds + bufB + aOff[5]);
            }, {});
        PHASE_I8(3,
            {
                aE = *(const int32x4*)(lds + bufB + aOff[6]);
                aO = *(const int32x4*)(lds + bufB + aOff[7]);
            },
            { asm volatile("s_waitcnt vmcnt(8)" ::: "memory"); });
    }
#undef PHASE_I8

    // ---- exact int32 -> f32 conversion (in place, bit-pattern reuse) ----
#pragma unroll
    for (int mf = 0; mf < 8; ++mf)
#pragma unroll
        for (int nf = 0; nf < 4; ++nf) {
            int32x4 vi = acc[mf][nf];
            f32x4 vf;
#pragma unroll
            for (int i = 0; i < 4; ++i) vf[i] = (float)vi[i];
            acc[mf][nf] = __builtin_bit_cast(int32x4, vf);
        }

    // ---- loop 2: 8 bf16 fp sub-tiles (K=32 each), r12 single-phase ----
    for (int vt = NT_I8; vt < NT_ALL; ++vt) {
        const int bufB = (vt & 3) << 15;
        const int sB = ((vt + 3) & 3) << 15;
        short8 bF[4], aF[8];
#pragma unroll
        for (int nf = 0; nf < 4; ++nf)
            bF[nf] = *(const short8*)(lds + bufB + bOff[nf]);
#pragma unroll
        for (int mf = 0; mf < 8; ++mf)
            aF[mf] = *(const short8*)(lds + bufB + aOff[mf]);

        if (vt + 3 < NT_ALL) {
#pragma unroll
            for (int j = 0; j < 4; ++j) stage_one(vt + 3, sB, j);
        }

        __builtin_amdgcn_s_setprio(1);
#pragma unroll
        for (int mf = 0; mf < 8; ++mf)
#pragma unroll
            for (int nf = 0; nf < 4; ++nf)
                acc[mf][nf] = __builtin_bit_cast(int32x4,
                    __builtin_amdgcn_mfma_f32_16x16x32_bf16(
                        aF[mf], bF[nf],
                        __builtin_bit_cast(f32x4, acc[mf][nf]), 0, 0, 0));
        __builtin_amdgcn_s_setprio(0);

        if (vt <= NT_ALL - 4)
            asm volatile("s_waitcnt vmcnt(8)" ::: "memory");
        else if (vt == NT_ALL - 3)
            asm volatile("s_waitcnt vmcnt(4)" ::: "memory");
        else if (vt == NT_ALL - 2)
            asm volatile("s_waitcnt vmcnt(0)" ::: "memory");
        __builtin_amdgcn_sched_barrier(0);
        __builtin_amdgcn_s_barrier();
        __builtin_amdgcn_sched_barrier(0);
    }

    // epilogue: out = sc*ws*acc + (zero + 8*sc)*reduced + bias
    const int cr4 = kg * 4;
#pragma unroll
    for (int mf = 0; mf < 8; ++mf) {
#pragma unroll
        for (int nf = 0; nf < 4; ++nf) {
            int n = tileN + wc * 64 + nf * 16 + r16;
            float ws = wscale[n];
            float rd = reduced[n];
            float bs = bias[n];
            f32x4 av = __builtin_bit_cast(f32x4, acc[mf][nf]);
#pragma unroll
            for (int i = 0; i < 4; ++i) {
                int m = tileM + wr * 128 + mf * 16 + cr4 + i;
                float sc = scale_ws[m];
                float zr = zero_ws[m];
                out[(size_t)m * OUT_FEAT + n] =
                    sc * ws * av[i]
                    + (zr + sc * 8.0f) * rd + bs;
            }
        }
    }
}

// ------------------------------------------------------------------ launch ---
extern "C" void kernel_launch(void* const* d_in, const int* in_sizes, int n_in,
                              void* d_out, int out_size, void* d_ws, size_t ws_size,
                              hipStream_t stream)
{
    const void* px = 0; const void* pw = 0; const void* pfpw = 0;
    const void* pii = 0; const void* pfi = 0;
    const void* p4096[3] = {0, 0, 0}; int n4096 = 0;
    for (int i = 0; i < n_in; ++i) {
        switch (in_sizes[i]) {
            case 16777216: px = d_in[i]; break;
            case 7864320:  pw = d_in[i]; break;
            case 1048576:  pfpw = d_in[i]; break;
            case 3840:     pii = d_in[i]; break;
            case 256:      pfi = d_in[i]; break;
            case 4096:     if (n4096 < 3) p4096[n4096++] = d_in[i]; break;
            default: break;
        }
    }
    if (!px || !pw || !pfpw || !pii || !pfi || n4096 != 3) return;

    const float* x       = (const float*)px;
    const int*   wpacked = (const int*)pw;
    const float* wscale  = (const float*)p4096[0];
    const float* reduced = (const float*)p4096[1];
    const float* bias    = (const float*)p4096[2];
    const float* fpw     = (const float*)pfpw;
    const int*   int_idx = (const int*)pii;
    const int*   fp_idx  = (const int*)pfi;
    float*       out     = (float*)d_out;

    if (ws_size < (size_t)WS_NEED) return;

    char* ws = (char*)d_ws;
    signed char*    Aq8 = (signed char*)(ws + AQ8_OFF);
    signed char*    Wb8 = (signed char*)(ws + WB8_OFF);
    __hip_bfloat16* Afp = (__hip_bfloat16*)(ws + AFP_OFF);
    __hip_bfloat16* Wfp = (__hip_bfloat16*)(ws + WFP_OFF);
    float* scale_ws     = (float*)(ws + SCALE_OFF);
    float* zero_ws      = (float*)(ws + ZERO_OFF);

    prep_kernel<<<TOKENS + OUT_FEAT, 256, 0, stream>>>(
        x, int_idx, fp_idx, wpacked, fpw, wscale,
        Aq8, Afp, Wb8, Wfp, scale_ws, zero_ws);
    gemm256_i8<<<256, 512, 0, stream>>>(Aq8, Afp, Wb8, Wfp,
                                        scale_ws, zero_ws,
                                        wscale, reduced, bias, out);
}